// Round 1
// baseline (2465.137 us; speedup 1.0000x reference)
//
#include <hip/hip_runtime.h>
#include <hip/hip_bf16.h>

// ---------------- problem constants ----------------
static constexpr int    TB   = 8;      // batch
static constexpr int    TT   = 512;    // seq len
static constexpr size_t CHSTR = 512*512;       // one conv channel plane
static constexpr size_t CBSTR = 30*CHSTR;      // one batch of 30 channels

// d_out offsets (in floats): S, dis, SeqtoBlur, avged_len
static constexpr size_t S_OFF    = 0;
static constexpr size_t DIS_OFF  = (size_t)8*512*512;            // 2097152
static constexpr size_t S2B_OFF  = DIS_OFF + 8;                  // 2097160
static constexpr size_t ALEN_OFF = S2B_OFF + (size_t)8*512*512;  // 4194312

// workspace offsets (in floats)
static constexpr size_t AVG_O  = 0;              // [8,512,512] avged_seq
static constexpr size_t H1_O   = 2097152;        // [8192,512]
static constexpr size_t H2_O   = 6291456;        // [8192,512]
static constexpr size_t EMB_O  = 10485760;       // [8192,128]  (q rows 0..4095, k rows 4096..)
static constexpr size_t SQN_O  = 11534336;       // [8192]
static constexpr size_t R_O    = 11542528;       // [8,512]
static constexpr size_t AR_O   = 11546624;       // [8,512]
static constexpr size_t D_O    = 11550720;       // [8,512,512]
static constexpr size_t A3_O   = 13647872;       // [8,512,512]
static constexpr size_t RDS_O  = 15745024;       // [4096]
static constexpr size_t RSS_O  = 15749120;       // [4096]
static constexpr size_t WT1_O  = 15753216;       // 1500 used
static constexpr size_t WT2_O  = 15754752;       // 22500 used
static constexpr size_t CB1_O  = 15777280;       // nb * CBSTR, then CB2 follows

// ---------------- prep: blur ----------------
__global__ __launch_bounds__(128) void prep_kernel(const float* __restrict__ seq,
    const int* __restrict__ len, float* __restrict__ avg) {
  int t = blockIdx.x, b = blockIdx.y, tid = threadIdx.x;
  int OL = len[b] - 2;
  size_t base = ((size_t)b*512 + t)*512 + tid*4;
  float4 v = make_float4(0.f,0.f,0.f,0.f);
  if (t < OL) {
    float4 a = *(const float4*)&seq[base];
    float4 c = *(const float4*)&seq[base + 512];
    float4 d = *(const float4*)&seq[base + 1024];
    v.x = 0.15f*a.x + 0.7f*c.x + 0.15f*d.x;
    v.y = 0.15f*a.y + 0.7f*c.y + 0.15f*d.y;
    v.z = 0.15f*a.z + 0.7f*c.z + 0.15f*d.z;
    v.w = 0.15f*a.w + 0.7f*c.w + 0.15f*d.w;
  }
  *(float4*)&avg[base] = v;
}

// ---------------- R / avged_R / avged_len ----------------
__global__ void rp_kernel(const int* __restrict__ len, float* __restrict__ R,
                          float* __restrict__ AR, float* __restrict__ alenOut) {
  int b = blockIdx.x, t = threadIdx.x;
  int L = len[b], OL = L - 2;
  R[b*512+t]  = (t < L)  ? (t+1.f)/(float)L  : 0.f;
  AR[b*512+t] = (t < OL) ? (t+1.f)/(float)OL : 0.f;
  if (t == 0) alenOut[b] = (float)OL;
}

// ---------------- SeqtoBlur ----------------
__global__ __launch_bounds__(128) void s2b_kernel(const int* __restrict__ len,
                                                  float* __restrict__ s2b) {
  int i = blockIdx.x, b = blockIdx.y, tid = threadIdx.x;
  int OL = len[b] - 2;
  int j0 = tid*4;
  float vals[4];
#pragma unroll
  for (int e = 0; e < 4; ++e) {
    int j = j0 + e;
    float x = 0.f;
    if (j < OL) {
      if (j == i)        x = 0.15f;
      else if (j == i-1) x = 0.7f;
      else if (j == i-2) x = 0.15f;
    }
    vals[e] = x;
  }
  *(float4*)&s2b[((size_t)b*512 + i)*512 + j0] =
      make_float4(vals[0],vals[1],vals[2],vals[3]);
}

// ---------------- conv weight transpose to [ic][ky][kx][oc] ----------------
__global__ void wtrans_kernel(const float* __restrict__ c1w, const float* __restrict__ c2w,
                              float* __restrict__ wT1, float* __restrict__ wT2) {
  int tid = threadIdx.x;
  for (int i = tid; i < 1500; i += 1024) {       // c1w [30][2][5][5]
    int oc = i / 50, r = i % 50, ic = r / 25, t = r % 25;
    wT1[(ic*25 + t)*30 + oc] = c1w[i];
  }
  for (int i = tid; i < 22500; i += 1024) {      // c2w [30][30][5][5]
    int oc = i / 750, r = i % 750, ic = r / 25, t = r % 25;
    wT2[(ic*25 + t)*30 + oc] = c2w[i];
  }
}

// ---------------- fp32 SGEMM: C = relu?(A[M,K] @ W[K,N] + bias) ----------------
template<bool RELU>
__global__ __launch_bounds__(256) void gemm_kernel(const float* __restrict__ A,
    const float* __restrict__ W, const float* __restrict__ bias,
    float* __restrict__ C, int M, int N, int K) {
  __shared__ float sA[16][64];
  __shared__ float sB[16][64];
  int tid = threadIdx.x;
  int tx = tid & 15, ty = tid >> 4;
  int rowBase = blockIdx.y * 64, colBase = blockIdx.x * 64;
  int lr = tid >> 2, lc = (tid & 3) * 4;
  int wr = tid >> 4, wc = (tid & 15) * 4;
  float acc[4][4] = {};
  for (int k0 = 0; k0 < K; k0 += 16) {
    float4 av = *(const float4*)&A[(size_t)(rowBase + lr)*K + k0 + lc];
    float4 wv = *(const float4*)&W[(size_t)(k0 + wr)*N + colBase + wc];
    sA[lc+0][lr] = av.x; sA[lc+1][lr] = av.y; sA[lc+2][lr] = av.z; sA[lc+3][lr] = av.w;
    *(float4*)&sB[wr][wc] = wv;
    __syncthreads();
#pragma unroll
    for (int k = 0; k < 16; ++k) {
      float4 a  = *(const float4*)&sA[k][ty*4];
      float4 b4 = *(const float4*)&sB[k][tx*4];
      float avv[4] = {a.x,a.y,a.z,a.w}, bvv[4] = {b4.x,b4.y,b4.z,b4.w};
#pragma unroll
      for (int i = 0; i < 4; ++i)
#pragma unroll
        for (int j = 0; j < 4; ++j)
          acc[i][j] = fmaf(avv[i], bvv[j], acc[i][j]);
    }
    __syncthreads();
  }
  float4 bv = *(const float4*)&bias[colBase + tx*4];
  float bb[4] = {bv.x, bv.y, bv.z, bv.w};
#pragma unroll
  for (int i = 0; i < 4; ++i) {
    int row = rowBase + ty*4 + i;
    float t0 = acc[i][0]+bb[0], t1 = acc[i][1]+bb[1], t2 = acc[i][2]+bb[2], t3 = acc[i][3]+bb[3];
    if (RELU) { t0=fmaxf(t0,0.f); t1=fmaxf(t1,0.f); t2=fmaxf(t2,0.f); t3=fmaxf(t3,0.f); }
    *(float4*)&C[(size_t)row*N + colBase + tx*4] = make_float4(t0,t1,t2,t3);
  }
}

// ---------------- L2 normalize rows of EMB [8192,128], record ||row||^2 ----------------
__global__ __launch_bounds__(64) void norm_kernel(float* __restrict__ EMB,
                                                  float* __restrict__ sqn) {
  int row = blockIdx.x, tid = threadIdx.x;
  size_t base = (size_t)row * 128;
  float v0 = EMB[base + tid], v1 = EMB[base + tid + 64];
  float ss = v0*v0 + v1*v1;
#pragma unroll
  for (int off = 32; off; off >>= 1) ss += __shfl_xor(ss, off);
  float n = sqrtf(ss);
  float inv = (n > 0.f) ? 1.f/n : 0.f;
  EMB[base + tid]      = v0 * inv;
  EMB[base + tid + 64] = v1 * inv;
  if (tid == 0) sqn[row] = ss * inv * inv;
}

// ---------------- D = cdist(emb_q, emb_k) per batch ----------------
__global__ __launch_bounds__(256) void dmat_kernel(const float* __restrict__ EMB,
    const float* __restrict__ sqn, float* __restrict__ Dm) {
  __shared__ float sq[64][68];
  __shared__ float sk[64][68];
  int tid = threadIdx.x, tx = tid & 15, ty = tid >> 4;
  int kBase = blockIdx.x * 64, qBase = blockIdx.y * 64, b = blockIdx.z;
  const float* Q  = EMB + (size_t)b * 512 * 128;
  const float* Kp = EMB + (size_t)(4096 + b*512) * 128;
  float acc[4][4] = {};
  for (int kc = 0; kc < 128; kc += 64) {
    __syncthreads();
    for (int idx = tid; idx < 64*16; idx += 256) {
      int r = idx >> 4, c4 = (idx & 15) * 4;
      *(float4*)&sq[r][c4] = *(const float4*)&Q[(size_t)(qBase + r)*128 + kc + c4];
      *(float4*)&sk[r][c4] = *(const float4*)&Kp[(size_t)(kBase + r)*128 + kc + c4];
    }
    __syncthreads();
#pragma unroll
    for (int kk = 0; kk < 64; kk += 4) {
      float4 a[4], bq[4];
#pragma unroll
      for (int i = 0; i < 4; ++i) a[i]  = *(const float4*)&sq[ty*4+i][kk];
#pragma unroll
      for (int j = 0; j < 4; ++j) bq[j] = *(const float4*)&sk[tx*4+j][kk];
#pragma unroll
      for (int i = 0; i < 4; ++i)
#pragma unroll
        for (int j = 0; j < 4; ++j)
          acc[i][j] += a[i].x*bq[j].x + a[i].y*bq[j].y + a[i].z*bq[j].z + a[i].w*bq[j].w;
    }
  }
#pragma unroll
  for (int i = 0; i < 4; ++i) {
    int q = qBase + ty*4 + i;
    float sqv = sqn[b*512 + q];
#pragma unroll
    for (int j = 0; j < 4; ++j) {
      int k = kBase + tx*4 + j;
      float skv = sqn[4096 + b*512 + k];
      float d2 = fmaxf(sqv + skv - 2.f*acc[i][j], 1e-12f);
      Dm[((size_t)b*512 + q)*512 + k] = sqrtf(d2);
    }
  }
}

// ---------------- conv1: in {D, P}, 5x5 pad2, 15 oc per pass, relu ----------------
__global__ __launch_bounds__(128) void conv1_kernel(const float* __restrict__ Dm,
    const float* __restrict__ R, const float* __restrict__ AR,
    float* __restrict__ cbout, const float* __restrict__ wT1,
    const float* __restrict__ bias, int oc0, int b0) {
  int slot = blockIdx.z, b = b0 + slot;
  int tx = threadIdx.x & 7, ty = threadIdx.x >> 3;
  int gx0 = blockIdx.x * 32, gy0 = blockIdx.y * 16;
  __shared__ float sIn[2][20][36];
  for (int i = threadIdx.x; i < 720; i += 128) {
    int r = i / 36, c = i - r*36;
    int gy = gy0 + r - 2, gx = gx0 + c - 2;
    float dv = 0.f, pv = 0.f;
    if ((unsigned)gy < 512u && (unsigned)gx < 512u) {
      dv = Dm[((size_t)b*512 + gy)*512 + gx];
      pv = fabsf(R[b*512+gy] - AR[b*512+gx]);
    }
    sIn[0][0][i] = dv;
    sIn[1][0][i] = pv;
  }
  __syncthreads();
  float acc[15][4] = {};
#pragma unroll
  for (int ic = 0; ic < 2; ++ic)
#pragma unroll
    for (int ky = 0; ky < 5; ++ky) {
      float4 va = *(const float4*)&sIn[ic][ty+ky][tx*4];
      float4 vb = *(const float4*)&sIn[ic][ty+ky][tx*4+4];
      float v[8] = {va.x,va.y,va.z,va.w,vb.x,vb.y,vb.z,vb.w};
#pragma unroll
      for (int kx = 0; kx < 5; ++kx) {
        const float* wp = wT1 + ((ic*5+ky)*5+kx)*30 + oc0;
#pragma unroll
        for (int oc = 0; oc < 15; ++oc) {
          float w = wp[oc];
#pragma unroll
          for (int p = 0; p < 4; ++p)
            acc[oc][p] = fmaf(v[p+kx], w, acc[oc][p]);
        }
      }
    }
  int gy = gy0 + ty, gx = gx0 + tx*4;
#pragma unroll
  for (int oc = 0; oc < 15; ++oc) {
    float bv = bias[oc0 + oc];
    float4 o = make_float4(fmaxf(acc[oc][0]+bv,0.f), fmaxf(acc[oc][1]+bv,0.f),
                           fmaxf(acc[oc][2]+bv,0.f), fmaxf(acc[oc][3]+bv,0.f));
    *(float4*)&cbout[(size_t)slot*CBSTR + (size_t)(oc0+oc)*CHSTR + (size_t)gy*512 + gx] = o;
  }
}

// ---------------- conv2: 30->30 5x5 pad2, 15 oc per pass, relu ----------------
__global__ __launch_bounds__(128) void conv2_kernel(const float* __restrict__ cbin,
    float* __restrict__ cbout, const float* __restrict__ wT2,
    const float* __restrict__ bias, int oc0) {
  int slot = blockIdx.z;
  int tx = threadIdx.x & 7, ty = threadIdx.x >> 3;
  int gx0 = blockIdx.x * 32, gy0 = blockIdx.y * 16;
  __shared__ float sIn[20][36];
  float acc[15][4] = {};
  const float* in = cbin + (size_t)slot*CBSTR;
  for (int ic = 0; ic < 30; ++ic) {
    __syncthreads();
    for (int i = threadIdx.x; i < 720; i += 128) {
      int r = i / 36, c = i - r*36;
      int gy = gy0 + r - 2, gx = gx0 + c - 2;
      float v = 0.f;
      if ((unsigned)gy < 512u && (unsigned)gx < 512u)
        v = in[(size_t)ic*CHSTR + (size_t)gy*512 + gx];
      sIn[0][i] = v;
    }
    __syncthreads();
#pragma unroll
    for (int ky = 0; ky < 5; ++ky) {
      float4 va = *(const float4*)&sIn[ty+ky][tx*4];
      float4 vb = *(const float4*)&sIn[ty+ky][tx*4+4];
      float v[8] = {va.x,va.y,va.z,va.w,vb.x,vb.y,vb.z,vb.w};
#pragma unroll
      for (int kx = 0; kx < 5; ++kx) {
        const float* wp = wT2 + ((ic*5+ky)*5+kx)*30 + oc0;
#pragma unroll
        for (int oc = 0; oc < 15; ++oc) {
          float w = wp[oc];
#pragma unroll
          for (int p = 0; p < 4; ++p)
            acc[oc][p] = fmaf(v[p+kx], w, acc[oc][p]);
        }
      }
    }
  }
  int gy = gy0 + ty, gx = gx0 + tx*4;
#pragma unroll
  for (int oc = 0; oc < 15; ++oc) {
    float bv = bias[oc0+oc];
    float4 o = make_float4(fmaxf(acc[oc][0]+bv,0.f), fmaxf(acc[oc][1]+bv,0.f),
                           fmaxf(acc[oc][2]+bv,0.f), fmaxf(acc[oc][3]+bv,0.f));
    *(float4*)&cbout[(size_t)slot*CBSTR + (size_t)(oc0+oc)*CHSTR + (size_t)gy*512 + gx] = o;
  }
}

// ---------------- conv3: 30->1 3x3 pad1, += D, no relu ----------------
__global__ __launch_bounds__(128) void conv3_kernel(const float* __restrict__ cbin,
    const float* __restrict__ Dm, const float* __restrict__ w3,
    const float* __restrict__ b3c, float* __restrict__ A3, int b0) {
  int slot = blockIdx.z, b = b0 + slot;
  int tx = threadIdx.x & 7, ty = threadIdx.x >> 3;
  int gx0 = blockIdx.x * 32, gy0 = blockIdx.y * 16;
  __shared__ float sIn[18][36];
  float acc[4] = {};
  const float* in = cbin + (size_t)slot*CBSTR;
  for (int ic = 0; ic < 30; ++ic) {
    __syncthreads();
    for (int i = threadIdx.x; i < 648; i += 128) {
      int r = i / 36, c = i - r*36;
      int gy = gy0 + r - 1, gx = gx0 + c - 1;
      float v = 0.f;
      if ((unsigned)gy < 512u && (unsigned)gx < 512u)
        v = in[(size_t)ic*CHSTR + (size_t)gy*512 + gx];
      sIn[0][i] = v;
    }
    __syncthreads();
#pragma unroll
    for (int ky = 0; ky < 3; ++ky) {
      float4 va = *(const float4*)&sIn[ty+ky][tx*4];
      float4 vb = *(const float4*)&sIn[ty+ky][tx*4+4];
      float v[8] = {va.x,va.y,va.z,va.w,vb.x,vb.y,vb.z,vb.w};
#pragma unroll
      for (int kx = 0; kx < 3; ++kx) {
        float w = w3[(ic*3+ky)*3+kx];
#pragma unroll
        for (int p = 0; p < 4; ++p)
          acc[p] = fmaf(v[p+kx], w, acc[p]);
      }
    }
  }
  int gy = gy0 + ty, gx = gx0 + tx*4;
  size_t base = ((size_t)b*512 + gy)*512 + gx;
  float bv = b3c[0];
  float4 dv = *(const float4*)&Dm[base];
  *(float4*)&A3[base] = make_float4(acc[0]+bv+dv.x, acc[1]+bv+dv.y,
                                    acc[2]+bv+dv.z, acc[3]+bv+dv.w);
}

// ---------------- softmax over k + per-row D*S and S sums ----------------
__global__ __launch_bounds__(256) void softmax_kernel(const float* __restrict__ A3,
    const float* __restrict__ Dm, float* __restrict__ S,
    float* __restrict__ rowDS, float* __restrict__ rowSS) {
  __shared__ float sred[4];
  __shared__ float sred2[4], sred3[4];
  int q = blockIdx.x, b = blockIdx.y, tid = threadIdx.x;
  size_t base = ((size_t)b*512 + q)*512;
  float x0 = -A3[base + tid], x1 = -A3[base + tid + 256];
  float m = fmaxf(x0, x1);
#pragma unroll
  for (int off = 32; off; off >>= 1) m = fmaxf(m, __shfl_xor(m, off));
  if ((tid & 63) == 0) sred[tid >> 6] = m;
  __syncthreads();
  m = fmaxf(fmaxf(sred[0], sred[1]), fmaxf(sred[2], sred[3]));
  __syncthreads();
  float p0 = expf(x0 - m), p1 = expf(x1 - m);
  float s = p0 + p1;
#pragma unroll
  for (int off = 32; off; off >>= 1) s += __shfl_xor(s, off);
  if ((tid & 63) == 0) sred[tid >> 6] = s;
  __syncthreads();
  s = sred[0] + sred[1] + sred[2] + sred[3];
  float inv = 1.f / s;
  float s0 = p0 * inv, s1 = p1 * inv;
  S[base + tid] = s0;
  S[base + tid + 256] = s1;
  float ds = s0*Dm[base + tid] + s1*Dm[base + tid + 256];
  float ssum = s0 + s1;
#pragma unroll
  for (int off = 32; off; off >>= 1) { ds += __shfl_xor(ds, off); ssum += __shfl_xor(ssum, off); }
  if ((tid & 63) == 0) { sred2[tid>>6] = ds; sred3[tid>>6] = ssum; }
  __syncthreads();
  if (tid == 0) {
    rowDS[b*512+q] = sred2[0]+sred2[1]+sred2[2]+sred2[3];
    rowSS[b*512+q] = sred3[0]+sred3[1]+sred3[2]+sred3[3];
  }
}

// ---------------- dis = sum(D*S) / sum(S) per batch ----------------
__global__ __launch_bounds__(512) void dis_kernel(const float* __restrict__ rowDS,
    const float* __restrict__ rowSS, float* __restrict__ disOut) {
  __shared__ float sd[8], se[8];
  int b = blockIdx.x, tid = threadIdx.x;
  float ds = rowDS[b*512 + tid];
  float ss = rowSS[b*512 + tid];
#pragma unroll
  for (int off = 32; off; off >>= 1) { ds += __shfl_xor(ds, off); ss += __shfl_xor(ss, off); }
  if ((tid & 63) == 0) { sd[tid>>6] = ds; se[tid>>6] = ss; }
  __syncthreads();
  if (tid == 0) {
    float a = 0.f, c = 0.f;
    for (int i = 0; i < 8; ++i) { a += sd[i]; c += se[i]; }
    disOut[b] = a / c;
  }
}

// ---------------- host ----------------
extern "C" void kernel_launch(void* const* d_in, const int* in_sizes, int n_in,
                              void* d_out, int out_size, void* d_ws, size_t ws_size,
                              hipStream_t stream) {
  const float* seq = (const float*)d_in[0];
  const int*   len = (const int*)d_in[1];
  const float* W1  = (const float*)d_in[2];  const float* b1 = (const float*)d_in[3];
  const float* W2  = (const float*)d_in[4];  const float* b2 = (const float*)d_in[5];
  const float* W3  = (const float*)d_in[6];  const float* b3 = (const float*)d_in[7];
  const float* c1w = (const float*)d_in[8];  const float* c1b = (const float*)d_in[9];
  const float* c2w = (const float*)d_in[10]; const float* c2b = (const float*)d_in[11];
  const float* c3w = (const float*)d_in[12]; const float* c3b = (const float*)d_in[13];
  float* out = (float*)d_out;
  float* ws  = (float*)d_ws;

  float* AVG = ws + AVG_O;
  float* H1  = ws + H1_O;
  float* H2  = ws + H2_O;
  float* EMB = ws + EMB_O;
  float* SQN = ws + SQN_O;
  float* Rb  = ws + R_O;
  float* ARb = ws + AR_O;
  float* Db  = ws + D_O;
  float* A3  = ws + A3_O;
  float* RDS = ws + RDS_O;
  float* RSS = ws + RSS_O;
  float* WT1 = ws + WT1_O;
  float* WT2 = ws + WT2_O;
  float* CB1 = ws + CB1_O;

  // choose how many batches the conv ping-pong buffers hold
  int nb = 1;
  if      (ws_size >= (CB1_O + 2*(size_t)8*CBSTR)*sizeof(float)) nb = 8;
  else if (ws_size >= (CB1_O + 2*(size_t)4*CBSTR)*sizeof(float)) nb = 4;
  else if (ws_size >= (CB1_O + 2*(size_t)2*CBSTR)*sizeof(float)) nb = 2;
  float* CB2 = CB1 + (size_t)nb*CBSTR;

  // prep
  prep_kernel<<<dim3(512,8), 128, 0, stream>>>(seq, len, AVG);
  rp_kernel<<<8, 512, 0, stream>>>(len, Rb, ARb, out + ALEN_OFF);
  s2b_kernel<<<dim3(512,8), 128, 0, stream>>>(len, out + S2B_OFF);
  wtrans_kernel<<<1, 1024, 0, stream>>>(c1w, c2w, WT1, WT2);

  // MLP (shared weights on seq rows 0..4095 and avged rows 4096..8191)
  gemm_kernel<true ><<<dim3(8, 64),  256, 0, stream>>>(seq, W1, b1, H1,            4096, 512, 512);
  gemm_kernel<true ><<<dim3(8, 64),  256, 0, stream>>>(AVG, W1, b1, H1 + (size_t)4096*512, 4096, 512, 512);
  gemm_kernel<true ><<<dim3(8, 128), 256, 0, stream>>>(H1,  W2, b2, H2,            8192, 512, 512);
  gemm_kernel<false><<<dim3(2, 128), 256, 0, stream>>>(H2,  W3, b3, EMB,           8192, 128, 512);
  norm_kernel<<<8192, 64, 0, stream>>>(EMB, SQN);

  // D
  dmat_kernel<<<dim3(8,8,8), 256, 0, stream>>>(EMB, SQN, Db);

  // conv stack (grouped by nb batches)
  for (int bb = 0; bb < 8; bb += nb) {
    dim3 g(16, 32, nb);
    conv1_kernel<<<g, 128, 0, stream>>>(Db, Rb, ARb, CB1, WT1, c1b, 0,  bb);
    conv1_kernel<<<g, 128, 0, stream>>>(Db, Rb, ARb, CB1, WT1, c1b, 15, bb);
    conv2_kernel<<<g, 128, 0, stream>>>(CB1, CB2, WT2, c2b, 0);
    conv2_kernel<<<g, 128, 0, stream>>>(CB1, CB2, WT2, c2b, 15);
    conv3_kernel<<<g, 128, 0, stream>>>(CB2, Db, c3w, c3b, A3, bb);
  }

  // softmax + dis
  softmax_kernel<<<dim3(512,8), 256, 0, stream>>>(A3, Db, out + S_OFF, RDS, RSS);
  dis_kernel<<<8, 512, 0, stream>>>(RDS, RSS, out + DIS_OFF);
}

// Round 2
// 664.081 us; speedup vs baseline: 3.7121x; 3.7121x over previous
//
#include <hip/hip_runtime.h>
#include <hip/hip_bf16.h>

// ---------------- problem constants ----------------
static constexpr size_t CHW = (size_t)512*512*32;   // one NHWC bf16 conv batch (elems)

// d_out offsets (in floats): S, dis, SeqtoBlur, avged_len
static constexpr size_t S_OFF    = 0;
static constexpr size_t DIS_OFF  = (size_t)8*512*512;
static constexpr size_t S2B_OFF  = DIS_OFF + 8;
static constexpr size_t ALEN_OFF = S2B_OFF + (size_t)8*512*512;

typedef __attribute__((ext_vector_type(8))) short bf16x8;
typedef __attribute__((ext_vector_type(4))) float f32x4;

__device__ __forceinline__ unsigned short rne_bf16(float x) {
  unsigned u = __builtin_bit_cast(unsigned, x);
  return (unsigned short)((u + 0x7FFFu + ((u >> 16) & 1u)) >> 16);
}
__device__ __forceinline__ void split_bf16(float x, unsigned short& hi, unsigned short& lo) {
  unsigned u = __builtin_bit_cast(unsigned, x);
  hi = (unsigned short)(u >> 16);
  float hif = __builtin_bit_cast(float, (unsigned)hi << 16);
  float l = x - hif;
  lo = (unsigned short)(__builtin_bit_cast(unsigned, l) >> 16);
}
__device__ __forceinline__ float bf2f(short s) {
  return __builtin_bit_cast(float, ((unsigned)(unsigned short)s) << 16);
}

// ---------------- prep: seq copy-split (z=0) / blur-split (z=1) into QK hi/lo ----------------
__global__ __launch_bounds__(128) void prep_split(const float* __restrict__ seq,
    const int* __restrict__ len, unsigned short* __restrict__ QKhi,
    unsigned short* __restrict__ QKlo) {
  int t = blockIdx.x, b = blockIdx.y, mode = blockIdx.z, tid = threadIdx.x;
  size_t base = ((size_t)b*512 + t)*512 + tid*4;
  float v[4] = {0.f, 0.f, 0.f, 0.f};
  if (mode == 0) {
    float4 a = *(const float4*)&seq[base];
    v[0]=a.x; v[1]=a.y; v[2]=a.z; v[3]=a.w;
  } else {
    int OL = len[b] - 2;
    if (t < OL) {
      float4 a = *(const float4*)&seq[base];
      float4 c = *(const float4*)&seq[base + 512];
      float4 d = *(const float4*)&seq[base + 1024];
      v[0] = 0.15f*a.x + 0.7f*c.x + 0.15f*d.x;
      v[1] = 0.15f*a.y + 0.7f*c.y + 0.15f*d.y;
      v[2] = 0.15f*a.z + 0.7f*c.z + 0.15f*d.z;
      v[3] = 0.15f*a.w + 0.7f*c.w + 0.15f*d.w;
    }
  }
  ushort4 h, l;
  split_bf16(v[0], h.x, l.x); split_bf16(v[1], h.y, l.y);
  split_bf16(v[2], h.z, l.z); split_bf16(v[3], h.w, l.w);
  size_t ob = ((size_t)(mode*4096 + b*512 + t))*512 + tid*4;
  *(ushort4*)&QKhi[ob] = h;
  *(ushort4*)&QKlo[ob] = l;
}

// ---------------- R / avged_R / avged_len ----------------
__global__ void rp_kernel(const int* __restrict__ len, float* __restrict__ R,
                          float* __restrict__ AR, float* __restrict__ alenOut) {
  int b = blockIdx.x, t = threadIdx.x;
  int L = len[b], OL = L - 2;
  R[b*512+t]  = (t < L)  ? (t+1.f)/(float)L  : 0.f;
  AR[b*512+t] = (t < OL) ? (t+1.f)/(float)OL : 0.f;
  if (t == 0) alenOut[b] = (float)OL;
}

// ---------------- SeqtoBlur ----------------
__global__ __launch_bounds__(128) void s2b_kernel(const int* __restrict__ len,
                                                  float* __restrict__ s2b) {
  int i = blockIdx.x, b = blockIdx.y, tid = threadIdx.x;
  int OL = len[b] - 2;
  int j0 = tid*4;
  float vals[4];
#pragma unroll
  for (int e = 0; e < 4; ++e) {
    int j = j0 + e;
    float x = 0.f;
    if (j < OL) {
      if (j == i)        x = 0.15f;
      else if (j == i-1) x = 0.7f;
      else if (j == i-2) x = 0.15f;
    }
    vals[e] = x;
  }
  *(float4*)&s2b[((size_t)b*512 + i)*512 + j0] =
      make_float4(vals[0],vals[1],vals[2],vals[3]);
}

// ---------------- conv weight prep ----------------
// WT1c: [ic][tap][oc30] fp32; WB2: [tap25][oc32][ic32] bf16 (zero pad); WT3: [tap9][ic32] fp32
__global__ void wtrans2_kernel(const float* __restrict__ c1w, const float* __restrict__ c2w,
                               const float* __restrict__ c3w, float* __restrict__ WT1c,
                               unsigned short* __restrict__ WB2, float* __restrict__ WT3) {
  int tid = threadIdx.x;
  for (int i = tid; i < 1500; i += 1024) {
    int oc = i / 50, r = i % 50, ic = r / 25, t = r % 25;
    WT1c[(ic*25 + t)*30 + oc] = c1w[i];     // c1w [oc30][ic2][5][5]
  }
  for (int i = tid; i < 25600; i += 1024) { // [tap][oc32][ic32]
    int tap = i >> 10, r = i & 1023, oc = r >> 5, ic = r & 31;
    float v = (oc < 30 && ic < 30) ? c2w[(size_t)(oc*30 + ic)*25 + tap] : 0.f;
    WB2[i] = rne_bf16(v);
  }
  for (int i = tid; i < 288; i += 1024) {   // [tap9][ic32]
    int tap = i >> 5, ic = i & 31;
    WT3[i] = (ic < 30) ? c3w[ic*9 + tap] : 0.f;  // c3w [1][ic30][3][3]
  }
}

// ---------------- weight split: W [K][N] fp32 -> WT hi/lo bf16 [N][K] ----------------
__global__ void wsplit_kernel(const float* __restrict__ W, unsigned short* __restrict__ Whi,
                              unsigned short* __restrict__ Wlo, int K, int N) {
  int n = blockIdx.x;
  for (int k = threadIdx.x; k < K; k += blockDim.x) {
    unsigned short h, l;
    split_bf16(W[(size_t)k*N + n], h, l);
    Whi[(size_t)n*K + k] = h;
    Wlo[(size_t)n*K + k] = l;
  }
}

// ---------------- split-bf16 MFMA GEMM: C = relu?(A @ B^T + bias) ----------------
// A given as hi/lo bf16 [M][K]; B as hi/lo bf16 [N][K]. 3-pass: hi*hi + hi*lo + lo*hi.
// OUTMODE 0: fp32 out, no relu. OUTMODE 1: bf16 hi/lo out, relu.
template<int OUTMODE>
__global__ __launch_bounds__(256) void gemm_hl(
    const unsigned short* __restrict__ Ahi, const unsigned short* __restrict__ Alo,
    const unsigned short* __restrict__ Bhi, const unsigned short* __restrict__ Blo,
    const float* __restrict__ bias, float* __restrict__ Cf,
    unsigned short* __restrict__ Chi, unsigned short* __restrict__ Clo,
    int M, int N, int K) {
  __shared__ short sAh[128*40], sAl[128*40], sBh[64*40], sBl[64*40];
  int tid = threadIdx.x, l = tid & 63, w = tid >> 6;
  int wm = w >> 1, wn = w & 1;
  int rowBase = blockIdx.y * 128, colBase = blockIdx.x * 64;
  int lr = l & 15, lc = l >> 4;
  f32x4 acc[4][2] = {};
  for (int k0 = 0; k0 < K; k0 += 32) {
    int idx = tid;
#pragma unroll
    for (int it = 0; it < 2; ++it, idx += 256) {
      int row = idx >> 2, c = (idx & 3) * 8;
      size_t g = (size_t)(rowBase + row) * K + k0 + c;
      *(bf16x8*)&sAh[row*40 + c] = *(const bf16x8*)&Ahi[g];
      *(bf16x8*)&sAl[row*40 + c] = *(const bf16x8*)&Alo[g];
    }
    {
      int row = tid >> 2, c = (tid & 3) * 8;
      if (row < 64) {
        size_t g = (size_t)(colBase + row) * K + k0 + c;
        *(bf16x8*)&sBh[row*40 + c] = *(const bf16x8*)&Bhi[g];
        *(bf16x8*)&sBl[row*40 + c] = *(const bf16x8*)&Blo[g];
      }
    }
    __syncthreads();
    bf16x8 ah[4], al[4], bh[2], bl[2];
#pragma unroll
    for (int m = 0; m < 4; ++m) {
      int r = wm*64 + m*16 + lr;
      ah[m] = *(const bf16x8*)&sAh[r*40 + lc*8];
      al[m] = *(const bf16x8*)&sAl[r*40 + lc*8];
    }
#pragma unroll
    for (int n = 0; n < 2; ++n) {
      int r = wn*32 + n*16 + lr;
      bh[n] = *(const bf16x8*)&sBh[r*40 + lc*8];
      bl[n] = *(const bf16x8*)&sBl[r*40 + lc*8];
    }
#pragma unroll
    for (int m = 0; m < 4; ++m)
#pragma unroll
      for (int n = 0; n < 2; ++n) {
        acc[m][n] = __builtin_amdgcn_mfma_f32_16x16x32_bf16(ah[m], bh[n], acc[m][n], 0, 0, 0);
        acc[m][n] = __builtin_amdgcn_mfma_f32_16x16x32_bf16(ah[m], bl[n], acc[m][n], 0, 0, 0);
        acc[m][n] = __builtin_amdgcn_mfma_f32_16x16x32_bf16(al[m], bh[n], acc[m][n], 0, 0, 0);
      }
    __syncthreads();
  }
#pragma unroll
  for (int m = 0; m < 4; ++m) {
    int row = rowBase + wm*64 + m*16 + lc*4;
#pragma unroll
    for (int n = 0; n < 2; ++n) {
      int col = colBase + wn*32 + n*16 + lr;
      float bv = bias[col];
#pragma unroll
      for (int j = 0; j < 4; ++j) {
        float v = acc[m][n][j] + bv;
        size_t o = (size_t)(row + j) * N + col;
        if (OUTMODE == 1) {
          v = fmaxf(v, 0.f);
          unsigned short h, lo;
          split_bf16(v, h, lo);
          Chi[o] = h; Clo[o] = lo;
        } else {
          Cf[o] = v;
        }
      }
    }
  }
}

// ---------------- L2 normalize rows of EMB [8192,128], record ||row||^2 ----------------
__global__ __launch_bounds__(64) void norm_kernel(float* __restrict__ EMB,
                                                  float* __restrict__ sqn) {
  int row = blockIdx.x, tid = threadIdx.x;
  size_t base = (size_t)row * 128;
  float v0 = EMB[base + tid], v1 = EMB[base + tid + 64];
  float ss = v0*v0 + v1*v1;
#pragma unroll
  for (int off = 32; off; off >>= 1) ss += __shfl_xor(ss, off);
  float n = sqrtf(ss);
  float inv = (n > 0.f) ? 1.f/n : 0.f;
  EMB[base + tid]      = v0 * inv;
  EMB[base + tid + 64] = v1 * inv;
  if (tid == 0) sqn[row] = ss * inv * inv;
}

// ---------------- D = cdist(emb_q, emb_k) per batch (fp32) ----------------
__global__ __launch_bounds__(256) void dmat_kernel(const float* __restrict__ EMB,
    const float* __restrict__ sqn, float* __restrict__ Dm) {
  __shared__ float sq[64][68];
  __shared__ float sk[64][68];
  int tid = threadIdx.x, tx = tid & 15, ty = tid >> 4;
  int kBase = blockIdx.x * 64, qBase = blockIdx.y * 64, b = blockIdx.z;
  const float* Q  = EMB + (size_t)b * 512 * 128;
  const float* Kp = EMB + (size_t)(4096 + b*512) * 128;
  float acc[4][4] = {};
  for (int kc = 0; kc < 128; kc += 64) {
    __syncthreads();
    for (int idx = tid; idx < 64*16; idx += 256) {
      int r = idx >> 4, c4 = (idx & 15) * 4;
      *(float4*)&sq[r][c4] = *(const float4*)&Q[(size_t)(qBase + r)*128 + kc + c4];
      *(float4*)&sk[r][c4] = *(const float4*)&Kp[(size_t)(kBase + r)*128 + kc + c4];
    }
    __syncthreads();
#pragma unroll
    for (int kk = 0; kk < 64; kk += 4) {
      float4 a[4], bq[4];
#pragma unroll
      for (int i = 0; i < 4; ++i) a[i]  = *(const float4*)&sq[ty*4+i][kk];
#pragma unroll
      for (int j = 0; j < 4; ++j) bq[j] = *(const float4*)&sk[tx*4+j][kk];
#pragma unroll
      for (int i = 0; i < 4; ++i)
#pragma unroll
        for (int j = 0; j < 4; ++j)
          acc[i][j] += a[i].x*bq[j].x + a[i].y*bq[j].y + a[i].z*bq[j].z + a[i].w*bq[j].w;
    }
  }
#pragma unroll
  for (int i = 0; i < 4; ++i) {
    int q = qBase + ty*4 + i;
    float sqv = sqn[b*512 + q];
#pragma unroll
    for (int j = 0; j < 4; ++j) {
      int k = kBase + tx*4 + j;
      float skv = sqn[4096 + b*512 + k];
      float d2 = fmaxf(sqv + skv - 2.f*acc[i][j], 1e-12f);
      Dm[((size_t)b*512 + q)*512 + k] = sqrtf(d2);
    }
  }
}

// ---------------- conv1: {D,P} -> 30ch NHWC bf16, 5x5 pad2, relu ----------------
__global__ __launch_bounds__(128) void conv1_nhwc(const float* __restrict__ Dm,
    const float* __restrict__ R, const float* __restrict__ AR,
    unsigned short* __restrict__ cbout, const float* __restrict__ WT1c,
    const float* __restrict__ bias, int b0) {
  int slot = blockIdx.z, b = b0 + slot;
  int tid = threadIdx.x, tx = tid & 15, ty = tid >> 4;   // ty 0..7, 2 px per thread
  int x0 = blockIdx.x * 16, y0 = blockIdx.y * 16;
  __shared__ float sD[20][20];
  __shared__ float sR[20], sAc[20];
  for (int i = tid; i < 400; i += 128) {
    int r = i / 20, c = i - r*20;
    int gy = y0 - 2 + r, gx = x0 - 2 + c;
    float v = 0.f;
    if ((unsigned)gy < 512u && (unsigned)gx < 512u)
      v = Dm[((size_t)b*512 + gy)*512 + gx];
    sD[r][c] = v;
  }
  if (tid < 20) {
    int gy = y0 - 2 + tid;
    sR[tid]  = ((unsigned)gy < 512u) ? R[b*512 + gy] : 0.f;
    int gx = x0 - 2 + tid;
    sAc[tid] = ((unsigned)gx < 512u) ? AR[b*512 + gx] : 0.f;
  }
  __syncthreads();
  float acc0[30] = {}, acc1[30] = {};
#pragma unroll
  for (int ky = 0; ky < 5; ++ky) {
#pragma unroll
    for (int kx = 0; kx < 5; ++kx) {
      float d0 = sD[ty+ky][tx+kx], d1 = sD[ty+8+ky][tx+kx];
      bool vx = (unsigned)(x0 + tx + kx - 2) < 512u;
      bool vy0 = (unsigned)(y0 + ty + ky - 2) < 512u;
      bool vy1 = (unsigned)(y0 + ty + 8 + ky - 2) < 512u;
      float p0 = (vx && vy0) ? fabsf(sR[ty+ky]   - sAc[tx+kx]) : 0.f;
      float p1 = (vx && vy1) ? fabsf(sR[ty+8+ky] - sAc[tx+kx]) : 0.f;
      const float* w0 = &WT1c[(0*25 + ky*5+kx)*30];
      const float* w1 = &WT1c[(1*25 + ky*5+kx)*30];
#pragma unroll
      for (int oc = 0; oc < 30; ++oc) {
        float wa = w0[oc], wb = w1[oc];
        acc0[oc] = fmaf(d0, wa, fmaf(p0, wb, acc0[oc]));
        acc1[oc] = fmaf(d1, wa, fmaf(p1, wb, acc1[oc]));
      }
    }
  }
  unsigned short* outp = cbout + (size_t)slot * CHW;
  {
    size_t ob = ((size_t)(y0 + ty)*512 + x0 + tx)*32;
#pragma unroll
    for (int oc = 0; oc < 30; ++oc)
      outp[ob + oc] = rne_bf16(fmaxf(acc0[oc] + bias[oc], 0.f));
    outp[ob+30] = 0; outp[ob+31] = 0;
  }
  {
    size_t ob = ((size_t)(y0 + ty + 8)*512 + x0 + tx)*32;
#pragma unroll
    for (int oc = 0; oc < 30; ++oc)
      outp[ob + oc] = rne_bf16(fmaxf(acc1[oc] + bias[oc], 0.f));
    outp[ob+30] = 0; outp[ob+31] = 0;
  }
}

// ---------------- conv2: 30->30 5x5 pad2 relu, bf16 MFMA over NHWC ----------------
// block: 256 thr (4 waves), out tile 32(y) x 16(x); wave w handles rows w*8..w*8+7.
// LDS tile [36 y][20 x][40 ch-pad] bf16 (px stride 80B -> 2-way free).
__global__ __launch_bounds__(256) void conv2_mfma(const unsigned short* __restrict__ cbin,
    unsigned short* __restrict__ cbout, const unsigned short* __restrict__ WB2,
    const float* __restrict__ bias) {
  __shared__ short tile[36*20*40];
  int tid = threadIdx.x, l = tid & 63, w = tid >> 6;
  int x0 = blockIdx.x * 16, y0 = blockIdx.y * 32, slot = blockIdx.z;
  const unsigned short* in = cbin + (size_t)slot * CHW;
  for (int idx = tid; idx < 2880; idx += 256) {
    int c = (idx & 3) * 8, px = idx >> 2;
    int r = px / 20, cc = px - r*20;
    int gy = y0 - 2 + r, gx = x0 - 2 + cc;
    bf16x8 v = {};
    if ((unsigned)gy < 512u && (unsigned)gx < 512u)
      v = *(const bf16x8*)&in[((size_t)gy*512 + gx)*32 + c];
    *(bf16x8*)&tile[(r*20 + cc)*40 + c] = v;
  }
  __syncthreads();
  int lr = l & 15, lc = l >> 4;
  f32x4 acc[8][2] = {};
  int wy = w * 8;
#pragma unroll
  for (int ky = 0; ky < 5; ++ky) {
#pragma unroll
    for (int kx = 0; kx < 5; ++kx) {
      int tap = ky*5 + kx;
      bf16x8 b0 = *(const bf16x8*)&WB2[(size_t)(tap*32 + lr)*32 + lc*8];
      bf16x8 b1 = *(const bf16x8*)&WB2[(size_t)(tap*32 + 16 + lr)*32 + lc*8];
#pragma unroll
      for (int g = 0; g < 8; ++g) {
        int rowL = wy + g + ky, colL = lr + kx;
        bf16x8 a = *(const bf16x8*)&tile[(rowL*20 + colL)*40 + lc*8];
        acc[g][0] = __builtin_amdgcn_mfma_f32_16x16x32_bf16(a, b0, acc[g][0], 0, 0, 0);
        acc[g][1] = __builtin_amdgcn_mfma_f32_16x16x32_bf16(a, b1, acc[g][1], 0, 0, 0);
      }
    }
  }
  unsigned short* outp = cbout + (size_t)slot * CHW;
  float bv0 = (lr < 30) ? bias[lr] : 0.f;
  float bv1 = 0.f;
  if (16 + lr < 30) bv1 = bias[16 + lr];
#pragma unroll
  for (int g = 0; g < 8; ++g) {
    int y = y0 + wy + g;
#pragma unroll
    for (int j = 0; j < 4; ++j) {
      int px = x0 + lc*4 + j;
      size_t ob = ((size_t)y*512 + px)*32;
      outp[ob + lr]      = rne_bf16(fmaxf(acc[g][0][j] + bv0, 0.f));
      outp[ob + 16 + lr] = rne_bf16(fmaxf(acc[g][1][j] + bv1, 0.f));
    }
  }
}

// ---------------- conv3: 30->1 3x3 pad1, += D + bias (fp32 math on bf16 NHWC) ----------------
__global__ __launch_bounds__(256) void conv3_nhwc(const unsigned short* __restrict__ cbin,
    const float* __restrict__ Dm, const float* __restrict__ WT3,
    const float* __restrict__ b3c, float* __restrict__ A3, int b0) {
  int slot = blockIdx.z, b = b0 + slot;
  int tid = threadIdx.x, tx = tid & 15, ty = tid >> 4;
  int x0 = blockIdx.x * 16, y0 = blockIdx.y * 16;
  __shared__ short tile[18*18*40];
  const unsigned short* in = cbin + (size_t)slot * CHW;
  for (int idx = tid; idx < 1296; idx += 256) {
    int c = (idx & 3) * 8, px = idx >> 2;
    int r = px / 18, cc = px - r*18;
    int gy = y0 - 1 + r, gx = x0 - 1 + cc;
    bf16x8 v = {};
    if ((unsigned)gy < 512u && (unsigned)gx < 512u)
      v = *(const bf16x8*)&in[((size_t)gy*512 + gx)*32 + c];
    *(bf16x8*)&tile[(r*18 + cc)*40 + c] = v;
  }
  __syncthreads();
  float acc = 0.f;
#pragma unroll
  for (int ky = 0; ky < 3; ++ky) {
#pragma unroll
    for (int kx = 0; kx < 3; ++kx) {
      const float* wp = &WT3[(ky*3 + kx)*32];
      int base = ((ty+ky)*18 + tx+kx)*40;
#pragma unroll
      for (int c = 0; c < 4; ++c) {
        bf16x8 v = *(const bf16x8*)&tile[base + c*8];
#pragma unroll
        for (int j = 0; j < 8; ++j)
          acc = fmaf(bf2f(v[j]), wp[c*8 + j], acc);
      }
    }
  }
  size_t o = ((size_t)b*512 + y0 + ty)*512 + x0 + tx;
  A3[o] = acc + b3c[0] + Dm[o];
}

// ---------------- softmax over k + per-row D*S and S sums ----------------
__global__ __launch_bounds__(256) void softmax_kernel(const float* __restrict__ A3,
    const float* __restrict__ Dm, float* __restrict__ S,
    float* __restrict__ rowDS, float* __restrict__ rowSS) {
  __shared__ float sred[4];
  __shared__ float sred2[4], sred3[4];
  int q = blockIdx.x, b = blockIdx.y, tid = threadIdx.x;
  size_t base = ((size_t)b*512 + q)*512;
  float x0 = -A3[base + tid], x1 = -A3[base + tid + 256];
  float m = fmaxf(x0, x1);
#pragma unroll
  for (int off = 32; off; off >>= 1) m = fmaxf(m, __shfl_xor(m, off));
  if ((tid & 63) == 0) sred[tid >> 6] = m;
  __syncthreads();
  m = fmaxf(fmaxf(sred[0], sred[1]), fmaxf(sred[2], sred[3]));
  __syncthreads();
  float p0 = expf(x0 - m), p1 = expf(x1 - m);
  float s = p0 + p1;
#pragma unroll
  for (int off = 32; off; off >>= 1) s += __shfl_xor(s, off);
  if ((tid & 63) == 0) sred[tid >> 6] = s;
  __syncthreads();
  s = sred[0] + sred[1] + sred[2] + sred[3];
  float inv = 1.f / s;
  float s0 = p0 * inv, s1 = p1 * inv;
  S[base + tid] = s0;
  S[base + tid + 256] = s1;
  float ds = s0*Dm[base + tid] + s1*Dm[base + tid + 256];
  float ssum = s0 + s1;
#pragma unroll
  for (int off = 32; off; off >>= 1) { ds += __shfl_xor(ds, off); ssum += __shfl_xor(ssum, off); }
  if ((tid & 63) == 0) { sred2[tid>>6] = ds; sred3[tid>>6] = ssum; }
  __syncthreads();
  if (tid == 0) {
    rowDS[b*512+q] = sred2[0]+sred2[1]+sred2[2]+sred2[3];
    rowSS[b*512+q] = sred3[0]+sred3[1]+sred3[2]+sred3[3];
  }
}

// ---------------- dis = sum(D*S) / sum(S) per batch ----------------
__global__ __launch_bounds__(512) void dis_kernel(const float* __restrict__ rowDS,
    const float* __restrict__ rowSS, float* __restrict__ disOut) {
  __shared__ float sd[8], se[8];
  int b = blockIdx.x, tid = threadIdx.x;
  float ds = rowDS[b*512 + tid];
  float ss = rowSS[b*512 + tid];
#pragma unroll
  for (int off = 32; off; off >>= 1) { ds += __shfl_xor(ds, off); ss += __shfl_xor(ss, off); }
  if ((tid & 63) == 0) { sd[tid>>6] = ds; se[tid>>6] = ss; }
  __syncthreads();
  if (tid == 0) {
    float a = 0.f, c = 0.f;
    for (int i = 0; i < 8; ++i) { a += sd[i]; c += se[i]; }
    disOut[b] = a / c;
  }
}

// ---------------- host ----------------
extern "C" void kernel_launch(void* const* d_in, const int* in_sizes, int n_in,
                              void* d_out, int out_size, void* d_ws, size_t ws_size,
                              hipStream_t stream) {
  const float* seq = (const float*)d_in[0];
  const int*   len = (const int*)d_in[1];
  const float* W1  = (const float*)d_in[2];  const float* b1 = (const float*)d_in[3];
  const float* W2  = (const float*)d_in[4];  const float* b2 = (const float*)d_in[5];
  const float* W3  = (const float*)d_in[6];  const float* b3 = (const float*)d_in[7];
  const float* c1w = (const float*)d_in[8];  const float* c1b = (const float*)d_in[9];
  const float* c2w = (const float*)d_in[10]; const float* c2b = (const float*)d_in[11];
  const float* c3w = (const float*)d_in[12]; const float* c3b = (const float*)d_in[13];
  float* out = (float*)d_out;
  char*  ws  = (char*)d_ws;

  size_t off = 0;
  auto alloc = [&](size_t bytes) { size_t o = off; off = (off + bytes + 255) & ~(size_t)255; return o; };
  const size_t MK2 = (size_t)8192*512*2;
  unsigned short* QKhi = (unsigned short*)(ws + alloc(MK2));
  unsigned short* QKlo = (unsigned short*)(ws + alloc(MK2));
  unsigned short* H1hi = (unsigned short*)(ws + alloc(MK2));
  unsigned short* H1lo = (unsigned short*)(ws + alloc(MK2));
  unsigned short* H2hi = (unsigned short*)(ws + alloc(MK2));
  unsigned short* H2lo = (unsigned short*)(ws + alloc(MK2));
  float* EMB = (float*)(ws + alloc((size_t)8192*128*4));
  float* SQN = (float*)(ws + alloc(8192*4));
  float* Rb  = (float*)(ws + alloc(4096*4));
  float* ARb = (float*)(ws + alloc(4096*4));
  float* Db  = (float*)(ws + alloc((size_t)8*512*512*4));
  float* A3  = (float*)(ws + alloc((size_t)8*512*512*4));
  float* RDS = (float*)(ws + alloc(4096*4));
  float* RSS = (float*)(ws + alloc(4096*4));
  unsigned short* W1Thi = (unsigned short*)(ws + alloc((size_t)512*512*2));
  unsigned short* W1Tlo = (unsigned short*)(ws + alloc((size_t)512*512*2));
  unsigned short* W2Thi = (unsigned short*)(ws + alloc((size_t)512*512*2));
  unsigned short* W2Tlo = (unsigned short*)(ws + alloc((size_t)512*512*2));
  unsigned short* W3Thi = (unsigned short*)(ws + alloc((size_t)128*512*2));
  unsigned short* W3Tlo = (unsigned short*)(ws + alloc((size_t)128*512*2));
  float* WT1c = (float*)(ws + alloc(1500*4));
  unsigned short* WB2 = (unsigned short*)(ws + alloc(25600*2));
  float* WT3 = (float*)(ws + alloc(288*4));
  size_t fixed = off;

  int nb = 1;
  const size_t CHB = CHW * 2;   // bytes per conv batch buffer
  if      (fixed + 2*(size_t)8*CHB <= ws_size) nb = 8;
  else if (fixed + 2*(size_t)4*CHB <= ws_size) nb = 4;
  else if (fixed + 2*(size_t)2*CHB <= ws_size) nb = 2;
  unsigned short* CB1 = (unsigned short*)(ws + alloc((size_t)nb*CHB));
  unsigned short* CB2 = (unsigned short*)(ws + alloc((size_t)nb*CHB));

  // prep + weights
  prep_split<<<dim3(512,8,2), 128, 0, stream>>>(seq, len, QKhi, QKlo);
  rp_kernel<<<8, 512, 0, stream>>>(len, Rb, ARb, out + ALEN_OFF);
  s2b_kernel<<<dim3(512,8), 128, 0, stream>>>(len, out + S2B_OFF);
  wtrans2_kernel<<<1, 1024, 0, stream>>>(c1w, c2w, c3w, WT1c, WB2, WT3);
  wsplit_kernel<<<512, 256, 0, stream>>>(W1, W1Thi, W1Tlo, 512, 512);
  wsplit_kernel<<<512, 256, 0, stream>>>(W2, W2Thi, W2Tlo, 512, 512);
  wsplit_kernel<<<128, 256, 0, stream>>>(W3, W3Thi, W3Tlo, 512, 128);

  // MLP (split-bf16 MFMA, ~fp32 accurate)
  gemm_hl<1><<<dim3(8, 64), 256, 0, stream>>>(QKhi, QKlo, W1Thi, W1Tlo, b1,
                                              nullptr, H1hi, H1lo, 8192, 512, 512);
  gemm_hl<1><<<dim3(8, 64), 256, 0, stream>>>(H1hi, H1lo, W2Thi, W2Tlo, b2,
                                              nullptr, H2hi, H2lo, 8192, 512, 512);
  gemm_hl<0><<<dim3(2, 64), 256, 0, stream>>>(H2hi, H2lo, W3Thi, W3Tlo, b3,
                                              EMB, nullptr, nullptr, 8192, 128, 512);
  norm_kernel<<<8192, 64, 0, stream>>>(EMB, SQN);
  dmat_kernel<<<dim3(8,8,8), 256, 0, stream>>>(EMB, SQN, Db);

  // conv stack
  for (int bb = 0; bb < 8; bb += nb) {
    conv1_nhwc<<<dim3(32,32,nb), 128, 0, stream>>>(Db, Rb, ARb, CB1, WT1c, c1b, bb);
    conv2_mfma<<<dim3(32,16,nb), 256, 0, stream>>>(CB1, CB2, WB2, c2b);
    conv3_nhwc<<<dim3(32,32,nb), 256, 0, stream>>>(CB2, Db, WT3, c3b, A3, bb);
  }

  softmax_kernel<<<dim3(512,8), 256, 0, stream>>>(A3, Db, out + S_OFF, RDS, RSS);
  dis_kernel<<<8, 512, 0, stream>>>(RDS, RSS, out + DIS_OFF);
}

// Round 3
// 383.777 us; speedup vs baseline: 6.4234x; 1.7304x over previous
//
#include <hip/hip_runtime.h>
#include <hip/hip_bf16.h>

// ---------------- problem constants ----------------
static constexpr size_t CHW = (size_t)512*512*32;   // one NHWC bf16 conv batch (elems)

// d_out offsets (in floats): S, dis, SeqtoBlur, avged_len
static constexpr size_t S_OFF    = 0;
static constexpr size_t DIS_OFF  = (size_t)8*512*512;
static constexpr size_t S2B_OFF  = DIS_OFF + 8;
static constexpr size_t ALEN_OFF = S2B_OFF + (size_t)8*512*512;

typedef __attribute__((ext_vector_type(8))) short bf16x8;
typedef __attribute__((ext_vector_type(4))) float f32x4;

__device__ __forceinline__ unsigned short rne_bf16(float x) {
  unsigned u = __builtin_bit_cast(unsigned, x);
  return (unsigned short)((u + 0x7FFFu + ((u >> 16) & 1u)) >> 16);
}
__device__ __forceinline__ void split_bf16(float x, unsigned short& hi, unsigned short& lo) {
  unsigned u = __builtin_bit_cast(unsigned, x);
  hi = (unsigned short)(u >> 16);
  float hif = __builtin_bit_cast(float, (unsigned)hi << 16);
  float l = x - hif;
  lo = (unsigned short)(__builtin_bit_cast(unsigned, l) >> 16);
}
__device__ __forceinline__ float bf2f(short s) {
  return __builtin_bit_cast(float, ((unsigned)(unsigned short)s) << 16);
}

// ---------------- prep: seq copy-split (z=0) / blur-split (z=1) into QK hi/lo ----------------
__global__ __launch_bounds__(128) void prep_split(const float* __restrict__ seq,
    const int* __restrict__ len, unsigned short* __restrict__ QKhi,
    unsigned short* __restrict__ QKlo) {
  int t = blockIdx.x, b = blockIdx.y, mode = blockIdx.z, tid = threadIdx.x;
  size_t base = ((size_t)b*512 + t)*512 + tid*4;
  float v[4] = {0.f, 0.f, 0.f, 0.f};
  if (mode == 0) {
    float4 a = *(const float4*)&seq[base];
    v[0]=a.x; v[1]=a.y; v[2]=a.z; v[3]=a.w;
  } else {
    int OL = len[b] - 2;
    if (t < OL) {
      float4 a = *(const float4*)&seq[base];
      float4 c = *(const float4*)&seq[base + 512];
      float4 d = *(const float4*)&seq[base + 1024];
      v[0] = 0.15f*a.x + 0.7f*c.x + 0.15f*d.x;
      v[1] = 0.15f*a.y + 0.7f*c.y + 0.15f*d.y;
      v[2] = 0.15f*a.z + 0.7f*c.z + 0.15f*d.z;
      v[3] = 0.15f*a.w + 0.7f*c.w + 0.15f*d.w;
    }
  }
  ushort4 h, l;
  split_bf16(v[0], h.x, l.x); split_bf16(v[1], h.y, l.y);
  split_bf16(v[2], h.z, l.z); split_bf16(v[3], h.w, l.w);
  size_t ob = ((size_t)(mode*4096 + b*512 + t))*512 + tid*4;
  *(ushort4*)&QKhi[ob] = h;
  *(ushort4*)&QKlo[ob] = l;
}

// ---------------- R / avged_R / avged_len ----------------
__global__ void rp_kernel(const int* __restrict__ len, float* __restrict__ R,
                          float* __restrict__ AR, float* __restrict__ alenOut) {
  int b = blockIdx.x, t = threadIdx.x;
  int L = len[b], OL = L - 2;
  R[b*512+t]  = (t < L)  ? (t+1.f)/(float)L  : 0.f;
  AR[b*512+t] = (t < OL) ? (t+1.f)/(float)OL : 0.f;
  if (t == 0) alenOut[b] = (float)OL;
}

// ---------------- SeqtoBlur ----------------
__global__ __launch_bounds__(128) void s2b_kernel(const int* __restrict__ len,
                                                  float* __restrict__ s2b) {
  int i = blockIdx.x, b = blockIdx.y, tid = threadIdx.x;
  int OL = len[b] - 2;
  int j0 = tid*4;
  float vals[4];
#pragma unroll
  for (int e = 0; e < 4; ++e) {
    int j = j0 + e;
    float x = 0.f;
    if (j < OL) {
      if (j == i)        x = 0.15f;
      else if (j == i-1) x = 0.7f;
      else if (j == i-2) x = 0.15f;
    }
    vals[e] = x;
  }
  *(float4*)&s2b[((size_t)b*512 + i)*512 + j0] =
      make_float4(vals[0],vals[1],vals[2],vals[3]);
}

// ---------------- conv weight prep ----------------
// WB1m: [28 tapslot][32 oc][8 ch] bf16 (ch0=D-weight, ch1=P-weight, rest 0; tapslot>=25 all 0)
// WB2:  [tap25][oc32][ic32] bf16 (zero pad); WT3: [tap9][ic32] fp32
__global__ void wtrans2_kernel(const float* __restrict__ c1w, const float* __restrict__ c2w,
                               const float* __restrict__ c3w, unsigned short* __restrict__ WB1m,
                               unsigned short* __restrict__ WB2, float* __restrict__ WT3) {
  int tid = threadIdx.x;
  for (int i = tid; i < 7168; i += 1024) {   // c1w [oc30][ic2][5][5]
    int ts = i >> 8, r = i & 255, oc = r >> 3, ch = r & 7;
    float v = 0.f;
    if (ts < 25 && oc < 30 && ch < 2) v = c1w[oc*50 + ch*25 + ts];
    WB1m[i] = rne_bf16(v);
  }
  for (int i = tid; i < 25600; i += 1024) { // [tap][oc32][ic32]
    int tap = i >> 10, r = i & 1023, oc = r >> 5, ic = r & 31;
    float v = (oc < 30 && ic < 30) ? c2w[(size_t)(oc*30 + ic)*25 + tap] : 0.f;
    WB2[i] = rne_bf16(v);
  }
  for (int i = tid; i < 288; i += 1024) {   // [tap9][ic32]
    int tap = i >> 5, ic = i & 31;
    WT3[i] = (ic < 30) ? c3w[ic*9 + tap] : 0.f;  // c3w [1][ic30][3][3]
  }
}

// ---------------- weight split: W [K][N] fp32 -> WT hi/lo bf16 [N][K] ----------------
__global__ void wsplit_kernel(const float* __restrict__ W, unsigned short* __restrict__ Whi,
                              unsigned short* __restrict__ Wlo, int K, int N) {
  int n = blockIdx.x;
  for (int k = threadIdx.x; k < K; k += blockDim.x) {
    unsigned short h, l;
    split_bf16(W[(size_t)k*N + n], h, l);
    Whi[(size_t)n*K + k] = h;
    Wlo[(size_t)n*K + k] = l;
  }
}

// ---------------- split-bf16 MFMA GEMM: C = relu?(A @ B^T + bias) ----------------
template<int OUTMODE>
__global__ __launch_bounds__(256) void gemm_hl(
    const unsigned short* __restrict__ Ahi, const unsigned short* __restrict__ Alo,
    const unsigned short* __restrict__ Bhi, const unsigned short* __restrict__ Blo,
    const float* __restrict__ bias, float* __restrict__ Cf,
    unsigned short* __restrict__ Chi, unsigned short* __restrict__ Clo,
    int M, int N, int K) {
  __shared__ short sAh[128*40], sAl[128*40], sBh[64*40], sBl[64*40];
  int tid = threadIdx.x, l = tid & 63, w = tid >> 6;
  int wm = w >> 1, wn = w & 1;
  int rowBase = blockIdx.y * 128, colBase = blockIdx.x * 64;
  int lr = l & 15, lc = l >> 4;
  f32x4 acc[4][2] = {};
  for (int k0 = 0; k0 < K; k0 += 32) {
    int idx = tid;
#pragma unroll
    for (int it = 0; it < 2; ++it, idx += 256) {
      int row = idx >> 2, c = (idx & 3) * 8;
      size_t g = (size_t)(rowBase + row) * K + k0 + c;
      *(bf16x8*)&sAh[row*40 + c] = *(const bf16x8*)&Ahi[g];
      *(bf16x8*)&sAl[row*40 + c] = *(const bf16x8*)&Alo[g];
    }
    {
      int row = tid >> 2, c = (tid & 3) * 8;
      if (row < 64) {
        size_t g = (size_t)(colBase + row) * K + k0 + c;
        *(bf16x8*)&sBh[row*40 + c] = *(const bf16x8*)&Bhi[g];
        *(bf16x8*)&sBl[row*40 + c] = *(const bf16x8*)&Blo[g];
      }
    }
    __syncthreads();
    bf16x8 ah[4], al[4], bh[2], bl[2];
#pragma unroll
    for (int m = 0; m < 4; ++m) {
      int r = wm*64 + m*16 + lr;
      ah[m] = *(const bf16x8*)&sAh[r*40 + lc*8];
      al[m] = *(const bf16x8*)&sAl[r*40 + lc*8];
    }
#pragma unroll
    for (int n = 0; n < 2; ++n) {
      int r = wn*32 + n*16 + lr;
      bh[n] = *(const bf16x8*)&sBh[r*40 + lc*8];
      bl[n] = *(const bf16x8*)&sBl[r*40 + lc*8];
    }
#pragma unroll
    for (int m = 0; m < 4; ++m)
#pragma unroll
      for (int n = 0; n < 2; ++n) {
        acc[m][n] = __builtin_amdgcn_mfma_f32_16x16x32_bf16(ah[m], bh[n], acc[m][n], 0, 0, 0);
        acc[m][n] = __builtin_amdgcn_mfma_f32_16x16x32_bf16(ah[m], bl[n], acc[m][n], 0, 0, 0);
        acc[m][n] = __builtin_amdgcn_mfma_f32_16x16x32_bf16(al[m], bh[n], acc[m][n], 0, 0, 0);
      }
    __syncthreads();
  }
#pragma unroll
  for (int m = 0; m < 4; ++m) {
    int row = rowBase + wm*64 + m*16 + lc*4;
#pragma unroll
    for (int n = 0; n < 2; ++n) {
      int col = colBase + wn*32 + n*16 + lr;
      float bv = bias[col];
#pragma unroll
      for (int j = 0; j < 4; ++j) {
        float v = acc[m][n][j] + bv;
        size_t o = (size_t)(row + j) * N + col;
        if (OUTMODE == 1) {
          v = fmaxf(v, 0.f);
          unsigned short h, lo;
          split_bf16(v, h, lo);
          Chi[o] = h; Clo[o] = lo;
        } else {
          Cf[o] = v;
        }
      }
    }
  }
}

// ---------------- L2 normalize rows of EMB [8192,128], record ||row||^2 ----------------
__global__ __launch_bounds__(64) void norm_kernel(float* __restrict__ EMB,
                                                  float* __restrict__ sqn) {
  int row = blockIdx.x, tid = threadIdx.x;
  size_t base = (size_t)row * 128;
  float v0 = EMB[base + tid], v1 = EMB[base + tid + 64];
  float ss = v0*v0 + v1*v1;
#pragma unroll
  for (int off = 32; off; off >>= 1) ss += __shfl_xor(ss, off);
  float n = sqrtf(ss);
  float inv = (n > 0.f) ? 1.f/n : 0.f;
  EMB[base + tid]      = v0 * inv;
  EMB[base + tid + 64] = v1 * inv;
  if (tid == 0) sqn[row] = ss * inv * inv;
}

// ---------------- D = cdist(emb_q, emb_k) per batch (fp32) ----------------
__global__ __launch_bounds__(256) void dmat_kernel(const float* __restrict__ EMB,
    const float* __restrict__ sqn, float* __restrict__ Dm) {
  __shared__ float sq[64][68];
  __shared__ float sk[64][68];
  int tid = threadIdx.x, tx = tid & 15, ty = tid >> 4;
  int kBase = blockIdx.x * 64, qBase = blockIdx.y * 64, b = blockIdx.z;
  const float* Q  = EMB + (size_t)b * 512 * 128;
  const float* Kp = EMB + (size_t)(4096 + b*512) * 128;
  float acc[4][4] = {};
  for (int kc = 0; kc < 128; kc += 64) {
    __syncthreads();
    for (int idx = tid; idx < 64*16; idx += 256) {
      int r = idx >> 4, c4 = (idx & 15) * 4;
      *(float4*)&sq[r][c4] = *(const float4*)&Q[(size_t)(qBase + r)*128 + kc + c4];
      *(float4*)&sk[r][c4] = *(const float4*)&Kp[(size_t)(kBase + r)*128 + kc + c4];
    }
    __syncthreads();
#pragma unroll
    for (int kk = 0; kk < 64; kk += 4) {
      float4 a[4], bq[4];
#pragma unroll
      for (int i = 0; i < 4; ++i) a[i]  = *(const float4*)&sq[ty*4+i][kk];
#pragma unroll
      for (int j = 0; j < 4; ++j) bq[j] = *(const float4*)&sk[tx*4+j][kk];
#pragma unroll
      for (int i = 0; i < 4; ++i)
#pragma unroll
        for (int j = 0; j < 4; ++j)
          acc[i][j] += a[i].x*bq[j].x + a[i].y*bq[j].y + a[i].z*bq[j].z + a[i].w*bq[j].w;
    }
  }
#pragma unroll
  for (int i = 0; i < 4; ++i) {
    int q = qBase + ty*4 + i;
    float sqv = sqn[b*512 + q];
#pragma unroll
    for (int j = 0; j < 4; ++j) {
      int k = kBase + tx*4 + j;
      float skv = sqn[4096 + b*512 + k];
      float d2 = fmaxf(sqv + skv - 2.f*acc[i][j], 1e-12f);
      Dm[((size_t)b*512 + q)*512 + k] = sqrtf(d2);
    }
  }
}

// ---------------- conv1: {D,P} -> 30ch NHWC bf16, 5x5 pad2, relu — MFMA, 4 taps/K32 ----------------
// block 256 thr (4 waves), out tile 32(y) x 16(x); wave w -> rows w*8..w*8+7.
// LDS tile [36 y][20 x][8 ch] bf16: ch0=D, ch1=P, rest 0. K = 4 taps x 8 slots.
__global__ __launch_bounds__(256) void conv1_mfma(const float* __restrict__ Dm,
    const float* __restrict__ R, const float* __restrict__ AR,
    unsigned short* __restrict__ cbout, const unsigned short* __restrict__ WB1m,
    const float* __restrict__ bias, int b0) {
  __shared__ short tile[36*20*8];
  int tid = threadIdx.x, l = tid & 63, w = tid >> 6;
  int x0 = blockIdx.x * 16, y0 = blockIdx.y * 32, slot = blockIdx.z;
  int b = b0 + slot;
  for (int i = tid; i < 720; i += 256) {
    int r = i / 20, c = i - r*20;
    int gy = y0 - 2 + r, gx = x0 - 2 + c;
    float dv = 0.f, pv = 0.f;
    if ((unsigned)gy < 512u && (unsigned)gx < 512u) {
      dv = Dm[((size_t)b*512 + gy)*512 + gx];
      pv = fabsf(R[b*512 + gy] - AR[b*512 + gx]);
    }
    bf16x8 v = {};
    v[0] = (short)rne_bf16(dv);
    v[1] = (short)rne_bf16(pv);
    *(bf16x8*)&tile[i*8] = v;
  }
  __syncthreads();
  int lr = l & 15, lc = l >> 4;
  f32x4 acc[8][2] = {};
  int wy = w * 8;
#pragma unroll
  for (int m = 0; m < 7; ++m) {
    int t = m*4 + lc;               // tap slot for this lane's K-group
    int ky = t / 5, kx = t - ky*5;
    bool valid = (t < 25);
    bf16x8 b0 = *(const bf16x8*)&WB1m[(size_t)t*256 + lr*8];
    bf16x8 b1 = *(const bf16x8*)&WB1m[(size_t)t*256 + (16 + lr)*8];
#pragma unroll
    for (int g = 0; g < 8; ++g) {
      bf16x8 a = {};
      if (valid) a = *(const bf16x8*)&tile[((wy + g + ky)*20 + lr + kx)*8];
      acc[g][0] = __builtin_amdgcn_mfma_f32_16x16x32_bf16(a, b0, acc[g][0], 0, 0, 0);
      acc[g][1] = __builtin_amdgcn_mfma_f32_16x16x32_bf16(a, b1, acc[g][1], 0, 0, 0);
    }
  }
  unsigned short* outp = cbout + (size_t)slot * CHW;
  float bv0 = bias[lr];
  float bv1 = (16 + lr < 30) ? bias[16 + lr] : 0.f;
#pragma unroll
  for (int g = 0; g < 8; ++g) {
    int y = y0 + wy + g;
#pragma unroll
    for (int j = 0; j < 4; ++j) {
      int px = x0 + lc*4 + j;
      size_t ob = ((size_t)y*512 + px)*32;
      outp[ob + lr]      = rne_bf16(fmaxf(acc[g][0][j] + bv0, 0.f));
      outp[ob + 16 + lr] = rne_bf16(fmaxf(acc[g][1][j] + bv1, 0.f));
    }
  }
}

// ---------------- conv2: 30->30 5x5 pad2 relu, bf16 MFMA over NHWC ----------------
__global__ __launch_bounds__(256) void conv2_mfma(const unsigned short* __restrict__ cbin,
    unsigned short* __restrict__ cbout, const unsigned short* __restrict__ WB2,
    const float* __restrict__ bias) {
  __shared__ short tile[36*20*40];
  int tid = threadIdx.x, l = tid & 63, w = tid >> 6;
  int x0 = blockIdx.x * 16, y0 = blockIdx.y * 32, slot = blockIdx.z;
  const unsigned short* in = cbin + (size_t)slot * CHW;
  for (int idx = tid; idx < 2880; idx += 256) {
    int c = (idx & 3) * 8, px = idx >> 2;
    int r = px / 20, cc = px - r*20;
    int gy = y0 - 2 + r, gx = x0 - 2 + cc;
    bf16x8 v = {};
    if ((unsigned)gy < 512u && (unsigned)gx < 512u)
      v = *(const bf16x8*)&in[((size_t)gy*512 + gx)*32 + c];
    *(bf16x8*)&tile[(r*20 + cc)*40 + c] = v;
  }
  __syncthreads();
  int lr = l & 15, lc = l >> 4;
  f32x4 acc[8][2] = {};
  int wy = w * 8;
#pragma unroll
  for (int ky = 0; ky < 5; ++ky) {
#pragma unroll
    for (int kx = 0; kx < 5; ++kx) {
      int tap = ky*5 + kx;
      bf16x8 b0 = *(const bf16x8*)&WB2[(size_t)(tap*32 + lr)*32 + lc*8];
      bf16x8 b1 = *(const bf16x8*)&WB2[(size_t)(tap*32 + 16 + lr)*32 + lc*8];
#pragma unroll
      for (int g = 0; g < 8; ++g) {
        int rowL = wy + g + ky, colL = lr + kx;
        bf16x8 a = *(const bf16x8*)&tile[(rowL*20 + colL)*40 + lc*8];
        acc[g][0] = __builtin_amdgcn_mfma_f32_16x16x32_bf16(a, b0, acc[g][0], 0, 0, 0);
        acc[g][1] = __builtin_amdgcn_mfma_f32_16x16x32_bf16(a, b1, acc[g][1], 0, 0, 0);
      }
    }
  }
  unsigned short* outp = cbout + (size_t)slot * CHW;
  float bv0 = (lr < 30) ? bias[lr] : 0.f;
  float bv1 = 0.f;
  if (16 + lr < 30) bv1 = bias[16 + lr];
#pragma unroll
  for (int g = 0; g < 8; ++g) {
    int y = y0 + wy + g;
#pragma unroll
    for (int j = 0; j < 4; ++j) {
      int px = x0 + lc*4 + j;
      size_t ob = ((size_t)y*512 + px)*32;
      outp[ob + lr]      = rne_bf16(fmaxf(acc[g][0][j] + bv0, 0.f));
      outp[ob + 16 + lr] = rne_bf16(fmaxf(acc[g][1][j] + bv1, 0.f));
    }
  }
}

// ---------------- conv3: 30->1 3x3 pad1, += D + bias (fp32 math on bf16 NHWC) ----------------
__global__ __launch_bounds__(256) void conv3_nhwc(const unsigned short* __restrict__ cbin,
    const float* __restrict__ Dm, const float* __restrict__ WT3,
    const float* __restrict__ b3c, float* __restrict__ A3, int b0) {
  int slot = blockIdx.z, b = b0 + slot;
  int tid = threadIdx.x, tx = tid & 15, ty = tid >> 4;
  int x0 = blockIdx.x * 16, y0 = blockIdx.y * 16;
  __shared__ short tile[18*18*40];
  const unsigned short* in = cbin + (size_t)slot * CHW;
  for (int idx = tid; idx < 1296; idx += 256) {
    int c = (idx & 3) * 8, px = idx >> 2;
    int r = px / 18, cc = px - r*18;
    int gy = y0 - 1 + r, gx = x0 - 1 + cc;
    bf16x8 v = {};
    if ((unsigned)gy < 512u && (unsigned)gx < 512u)
      v = *(const bf16x8*)&in[((size_t)gy*512 + gx)*32 + c];
    *(bf16x8*)&tile[(r*18 + cc)*40 + c] = v;
  }
  __syncthreads();
  float acc = 0.f;
#pragma unroll
  for (int ky = 0; ky < 3; ++ky) {
#pragma unroll
    for (int kx = 0; kx < 3; ++kx) {
      const float* wp = &WT3[(ky*3 + kx)*32];
      int base = ((ty+ky)*18 + tx+kx)*40;
#pragma unroll
      for (int c = 0; c < 4; ++c) {
        bf16x8 v = *(const bf16x8*)&tile[base + c*8];
#pragma unroll
        for (int j = 0; j < 8; ++j)
          acc = fmaf(bf2f(v[j]), wp[c*8 + j], acc);
      }
    }
  }
  size_t o = ((size_t)b*512 + y0 + ty)*512 + x0 + tx;
  A3[o] = acc + b3c[0] + Dm[o];
}

// ---------------- softmax over k + per-row D*S and S sums ----------------
__global__ __launch_bounds__(256) void softmax_kernel(const float* __restrict__ A3,
    const float* __restrict__ Dm, float* __restrict__ S,
    float* __restrict__ rowDS, float* __restrict__ rowSS) {
  __shared__ float sred[4];
  __shared__ float sred2[4], sred3[4];
  int q = blockIdx.x, b = blockIdx.y, tid = threadIdx.x;
  size_t base = ((size_t)b*512 + q)*512;
  float x0 = -A3[base + tid], x1 = -A3[base + tid + 256];
  float m = fmaxf(x0, x1);
#pragma unroll
  for (int off = 32; off; off >>= 1) m = fmaxf(m, __shfl_xor(m, off));
  if ((tid & 63) == 0) sred[tid >> 6] = m;
  __syncthreads();
  m = fmaxf(fmaxf(sred[0], sred[1]), fmaxf(sred[2], sred[3]));
  __syncthreads();
  float p0 = expf(x0 - m), p1 = expf(x1 - m);
  float s = p0 + p1;
#pragma unroll
  for (int off = 32; off; off >>= 1) s += __shfl_xor(s, off);
  if ((tid & 63) == 0) sred[tid >> 6] = s;
  __syncthreads();
  s = sred[0] + sred[1] + sred[2] + sred[3];
  float inv = 1.f / s;
  float s0 = p0 * inv, s1 = p1 * inv;
  S[base + tid] = s0;
  S[base + tid + 256] = s1;
  float ds = s0*Dm[base + tid] + s1*Dm[base + tid + 256];
  float ssum = s0 + s1;
#pragma unroll
  for (int off = 32; off; off >>= 1) { ds += __shfl_xor(ds, off); ssum += __shfl_xor(ssum, off); }
  if ((tid & 63) == 0) { sred2[tid>>6] = ds; sred3[tid>>6] = ssum; }
  __syncthreads();
  if (tid == 0) {
    rowDS[b*512+q] = sred2[0]+sred2[1]+sred2[2]+sred2[3];
    rowSS[b*512+q] = sred3[0]+sred3[1]+sred3[2]+sred3[3];
  }
}

// ---------------- dis = sum(D*S) / sum(S) per batch ----------------
__global__ __launch_bounds__(512) void dis_kernel(const float* __restrict__ rowDS,
    const float* __restrict__ rowSS, float* __restrict__ disOut) {
  __shared__ float sd[8], se[8];
  int b = blockIdx.x, tid = threadIdx.x;
  float ds = rowDS[b*512 + tid];
  float ss = rowSS[b*512 + tid];
#pragma unroll
  for (int off = 32; off; off >>= 1) { ds += __shfl_xor(ds, off); ss += __shfl_xor(ss, off); }
  if ((tid & 63) == 0) { sd[tid>>6] = ds; se[tid>>6] = ss; }
  __syncthreads();
  if (tid == 0) {
    float a = 0.f, c = 0.f;
    for (int i = 0; i < 8; ++i) { a += sd[i]; c += se[i]; }
    disOut[b] = a / c;
  }
}

// ---------------- host ----------------
extern "C" void kernel_launch(void* const* d_in, const int* in_sizes, int n_in,
                              void* d_out, int out_size, void* d_ws, size_t ws_size,
                              hipStream_t stream) {
  const float* seq = (const float*)d_in[0];
  const int*   len = (const int*)d_in[1];
  const float* W1  = (const float*)d_in[2];  const float* b1 = (const float*)d_in[3];
  const float* W2  = (const float*)d_in[4];  const float* b2 = (const float*)d_in[5];
  const float* W3  = (const float*)d_in[6];  const float* b3 = (const float*)d_in[7];
  const float* c1w = (const float*)d_in[8];  const float* c1b = (const float*)d_in[9];
  const float* c2w = (const float*)d_in[10]; const float* c2b = (const float*)d_in[11];
  const float* c3w = (const float*)d_in[12]; const float* c3b = (const float*)d_in[13];
  float* out = (float*)d_out;
  char*  ws  = (char*)d_ws;

  size_t off = 0;
  auto alloc = [&](size_t bytes) { size_t o = off; off = (off + bytes + 255) & ~(size_t)255; return o; };
  const size_t MK2 = (size_t)8192*512*2;
  unsigned short* QKhi = (unsigned short*)(ws + alloc(MK2));
  unsigned short* QKlo = (unsigned short*)(ws + alloc(MK2));
  unsigned short* H1hi = (unsigned short*)(ws + alloc(MK2));
  unsigned short* H1lo = (unsigned short*)(ws + alloc(MK2));
  unsigned short* H2hi = (unsigned short*)(ws + alloc(MK2));
  unsigned short* H2lo = (unsigned short*)(ws + alloc(MK2));
  float* EMB = (float*)(ws + alloc((size_t)8192*128*4));
  float* SQN = (float*)(ws + alloc(8192*4));
  float* Rb  = (float*)(ws + alloc(4096*4));
  float* ARb = (float*)(ws + alloc(4096*4));
  float* Db  = (float*)(ws + alloc((size_t)8*512*512*4));
  float* A3  = (float*)(ws + alloc((size_t)8*512*512*4));
  float* RDS = (float*)(ws + alloc(4096*4));
  float* RSS = (float*)(ws + alloc(4096*4));
  unsigned short* W1Thi = (unsigned short*)(ws + alloc((size_t)512*512*2));
  unsigned short* W1Tlo = (unsigned short*)(ws + alloc((size_t)512*512*2));
  unsigned short* W2Thi = (unsigned short*)(ws + alloc((size_t)512*512*2));
  unsigned short* W2Tlo = (unsigned short*)(ws + alloc((size_t)512*512*2));
  unsigned short* W3Thi = (unsigned short*)(ws + alloc((size_t)128*512*2));
  unsigned short* W3Tlo = (unsigned short*)(ws + alloc((size_t)128*512*2));
  unsigned short* WB1m = (unsigned short*)(ws + alloc(7168*2));
  unsigned short* WB2 = (unsigned short*)(ws + alloc(25600*2));
  float* WT3 = (float*)(ws + alloc(288*4));
  size_t fixed = off;

  int nb = 1;
  const size_t CHB = CHW * 2;   // bytes per conv batch buffer
  if      (fixed + 2*(size_t)8*CHB <= ws_size) nb = 8;
  else if (fixed + 2*(size_t)4*CHB <= ws_size) nb = 4;
  else if (fixed + 2*(size_t)2*CHB <= ws_size) nb = 2;
  unsigned short* CB1 = (unsigned short*)(ws + alloc((size_t)nb*CHB));
  unsigned short* CB2 = (unsigned short*)(ws + alloc((size_t)nb*CHB));

  // prep + weights
  prep_split<<<dim3(512,8,2), 128, 0, stream>>>(seq, len, QKhi, QKlo);
  rp_kernel<<<8, 512, 0, stream>>>(len, Rb, ARb, out + ALEN_OFF);
  s2b_kernel<<<dim3(512,8), 128, 0, stream>>>(len, out + S2B_OFF);
  wtrans2_kernel<<<1, 1024, 0, stream>>>(c1w, c2w, c3w, WB1m, WB2, WT3);
  wsplit_kernel<<<512, 256, 0, stream>>>(W1, W1Thi, W1Tlo, 512, 512);
  wsplit_kernel<<<512, 256, 0, stream>>>(W2, W2Thi, W2Tlo, 512, 512);
  wsplit_kernel<<<128, 256, 0, stream>>>(W3, W3Thi, W3Tlo, 512, 128);

  // MLP (split-bf16 MFMA, ~fp32 accurate)
  gemm_hl<1><<<dim3(8, 64), 256, 0, stream>>>(QKhi, QKlo, W1Thi, W1Tlo, b1,
                                              nullptr, H1hi, H1lo, 8192, 512, 512);
  gemm_hl<1><<<dim3(8, 64), 256, 0, stream>>>(H1hi, H1lo, W2Thi, W2Tlo, b2,
                                              nullptr, H2hi, H2lo, 8192, 512, 512);
  gemm_hl<0><<<dim3(2, 64), 256, 0, stream>>>(H2hi, H2lo, W3Thi, W3Tlo, b3,
                                              EMB, nullptr, nullptr, 8192, 128, 512);
  norm_kernel<<<8192, 64, 0, stream>>>(EMB, SQN);
  dmat_kernel<<<dim3(8,8,8), 256, 0, stream>>>(EMB, SQN, Db);

  // conv stack
  for (int bb = 0; bb < 8; bb += nb) {
    conv1_mfma<<<dim3(32,16,nb), 256, 0, stream>>>(Db, Rb, ARb, CB1, WB1m, c1b, bb);
    conv2_mfma<<<dim3(32,16,nb), 256, 0, stream>>>(CB1, CB2, WB2, c2b);
    conv3_nhwc<<<dim3(32,32,nb), 256, 0, stream>>>(CB2, Db, WT3, c3b, A3, bb);
  }

  softmax_kernel<<<dim3(512,8), 256, 0, stream>>>(A3, Db, out + S_OFF, RDS, RSS);
  dis_kernel<<<8, 512, 0, stream>>>(RDS, RSS, out + DIS_OFF);
}